// Round 1
// baseline (2854.863 us; speedup 1.0000x reference)
//
#include <hip/hip_runtime.h>
#include <math.h>

// Problem constants (B=8, N=1024, C=1024, H=16, hd=64, n_tasks=10, n_frq=3000)
#define NFRQ 3000

// ---------------------------------------------------------------------------
// DCT-II orthonormal matrix, computed in double for accuracy headroom.
__global__ __launch_bounds__(256) void dct_kernel(float* __restrict__ Bm) {
  int t = blockIdx.x * 256 + threadIdx.x;       // 0 .. 1M-1
  int i = t >> 10, j = t & 1023;
  double v;
  if (i == 0)
    v = sqrt(1.0 / 1024.0);
  else
    v = sqrt(2.0 / 1024.0) *
        cos(3.14159265358979323846 * (double)i * (2.0 * (double)j + 1.0) / 2048.0);
  Bm[t] = (float)v;
}

// ---------------------------------------------------------------------------
// U = S @ Bm where S is the sparse scatter of coef at idx (tasks 0..*task).
// One block per nonzero: U[r,:] += val * Bm[c,:]
__global__ __launch_bounds__(256) void scatter_kernel(const float* __restrict__ coef,
                                                      const int* __restrict__ idx,
                                                      const int* __restrict__ task,
                                                      const float* __restrict__ Bm,
                                                      float* __restrict__ U) {
  int nz = blockIdx.x;                          // 0 .. 29999
  if (nz / NFRQ > *task) return;                // tasks 0..task participate
  float val = coef[nz];
  int id = idx[nz];
  int r = id >> 10, c = id & 1023;
  const float* brow = Bm + ((size_t)c << 10);
  float* urow = U + ((size_t)r << 10);
  for (int j = (int)threadIdx.x; j < 1024; j += 256)
    atomicAdd(urow + j, val * brow[j]);
}

// ---------------------------------------------------------------------------
// C[MxN] = A^T B : A is KxM (lda=M), B is KxN (ldb=N). 64x64 tile, 4x4/thread.
__global__ __launch_bounds__(256) void gemm_tn(const float* __restrict__ A,
                                               const float* __restrict__ B,
                                               float* __restrict__ C,
                                               int K, int lda, int ldb, int ldc) {
  __shared__ float As[16][68];
  __shared__ float Bs[16][68];
  int t = threadIdx.x;
  int tx = t & 15, ty = t >> 4;
  int m0 = blockIdx.y * 64, n0 = blockIdx.x * 64;
  int kr = t >> 4;            // 0..15 : tile row
  int mc = (t & 15) << 2;     // 0..60 : tile col (x4)
  float acc[4][4] = {};
  for (int k0 = 0; k0 < K; k0 += 16) {
    float4 a4 = *(const float4*)(A + (size_t)(k0 + kr) * lda + m0 + mc);
    float4 b4 = *(const float4*)(B + (size_t)(k0 + kr) * ldb + n0 + mc);
    __syncthreads();
    *(float4*)&As[kr][mc] = a4;
    *(float4*)&Bs[kr][mc] = b4;
    __syncthreads();
#pragma unroll
    for (int k = 0; k < 16; ++k) {
      float ar[4], br[4];
#pragma unroll
      for (int i = 0; i < 4; ++i) ar[i] = As[k][ty * 4 + i];
#pragma unroll
      for (int j = 0; j < 4; ++j) br[j] = Bs[k][tx * 4 + j];
#pragma unroll
      for (int i = 0; i < 4; ++i)
#pragma unroll
        for (int j = 0; j < 4; ++j) acc[i][j] += ar[i] * br[j];
    }
  }
#pragma unroll
  for (int i = 0; i < 4; ++i) {
    float* crow = C + (size_t)(m0 + ty * 4 + i) * ldc + n0 + tx * 4;
#pragma unroll
    for (int j = 0; j < 4; ++j) crow[j] = acc[i][j];
  }
}

// ---------------------------------------------------------------------------
// C[MxN] (+)= A B^T : A is MxK (lda), B is NxK (ldb). 64x64 tile, 4x4/thread.
// beta!=0 -> accumulate into C; bias!=null -> add bias[col].
__global__ __launch_bounds__(256) void gemm_nt(const float* __restrict__ A,
                                               const float* __restrict__ B,
                                               float* __restrict__ C,
                                               int K, int lda, int ldb, int ldc,
                                               int beta, const float* __restrict__ bias) {
  __shared__ float As[16][65];   // As[k][m] (stored transposed)
  __shared__ float Bs[16][65];   // Bs[k][n]
  int t = threadIdx.x;
  int tx = t & 15, ty = t >> 4;
  int m0 = blockIdx.y * 64, n0 = blockIdx.x * 64;
  int lr = t >> 2;            // 0..63 : tile row
  int lc = (t & 3) << 2;      // 0,4,8,12 : k offset (x4)
  const float* aptr = A + (size_t)(m0 + lr) * lda + lc;
  const float* bptr = B + (size_t)(n0 + lr) * ldb + lc;
  float acc[4][4] = {};
  for (int k0 = 0; k0 < K; k0 += 16) {
    float4 a4 = *(const float4*)(aptr + k0);
    float4 b4 = *(const float4*)(bptr + k0);
    __syncthreads();
    As[lc + 0][lr] = a4.x; As[lc + 1][lr] = a4.y;
    As[lc + 2][lr] = a4.z; As[lc + 3][lr] = a4.w;
    Bs[lc + 0][lr] = b4.x; Bs[lc + 1][lr] = b4.y;
    Bs[lc + 2][lr] = b4.z; Bs[lc + 3][lr] = b4.w;
    __syncthreads();
#pragma unroll
    for (int k = 0; k < 16; ++k) {
      float ar[4], br[4];
#pragma unroll
      for (int i = 0; i < 4; ++i) ar[i] = As[k][ty * 4 + i];
#pragma unroll
      for (int j = 0; j < 4; ++j) br[j] = Bs[k][tx * 4 + j];
#pragma unroll
      for (int i = 0; i < 4; ++i)
#pragma unroll
        for (int j = 0; j < 4; ++j) acc[i][j] += ar[i] * br[j];
    }
  }
#pragma unroll
  for (int i = 0; i < 4; ++i) {
    float* crow = C + (size_t)(m0 + ty * 4 + i) * ldc + n0 + tx * 4;
#pragma unroll
    for (int j = 0; j < 4; ++j) {
      float v = acc[i][j];
      if (bias) v += bias[n0 + tx * 4 + j];
      if (beta) v += crow[j];
      crow[j] = v;
    }
  }
}

// ---------------------------------------------------------------------------
// Flash-style attention. qkv: (8*1024) x 3072 [q | k | v bands of 1024 cols].
// One block = one (b,h) and a 64-row q tile. Writes softmax(qk^T*s)@v into the
// q band in-place (each block writes exactly the cells only it has read).
__global__ __launch_bounds__(256) void attn_kernel(float* qkv) {
  const int LD = 3072, Nn = 1024, HDm = 64;
  __shared__ float qs[64][64];   // transposed: qs[d][i]
  __shared__ float ks[64][64];   // transposed: ks[d][j]
  __shared__ float vs[64][64];   // row-major:  vs[j][d]
  __shared__ float ps[64][64];   // swizzled:   ps[i][(j+4i)&63]
  int t = threadIdx.x;
  int tx = t & 15, ty = t >> 4;
  int b = blockIdx.y >> 4, h = blockIdx.y & 15;
  int q0 = blockIdx.x * 64;
  const float scale = 0.125f;    // hd^-0.5
  size_t base = (size_t)b * Nn * LD;

  // load q tile (transposed into LDS)
  {
    int i = t >> 2, c0 = (t & 3) << 4;
    const float* src = qkv + base + (size_t)(q0 + i) * LD + h * HDm + c0;
#pragma unroll
    for (int v4 = 0; v4 < 4; ++v4) {
      float4 f = ((const float4*)src)[v4];
      qs[c0 + v4 * 4 + 0][i] = f.x;
      qs[c0 + v4 * 4 + 1][i] = f.y;
      qs[c0 + v4 * 4 + 2][i] = f.z;
      qs[c0 + v4 * 4 + 3][i] = f.w;
    }
  }

  float m_i[4], l_i[4], o[4][4];
#pragma unroll
  for (int i = 0; i < 4; ++i) {
    m_i[i] = -INFINITY; l_i[i] = 0.f;
#pragma unroll
    for (int d = 0; d < 4; ++d) o[i][d] = 0.f;
  }

  for (int kt = 0; kt < 16; ++kt) {
    int kr0 = kt * 64;
    __syncthreads();   // prev iter done with ks/vs/ps (also covers q-store @kt=0)
    {
      int j = t >> 2, c0 = (t & 3) << 4;
      const float* ksrc = qkv + base + (size_t)(kr0 + j) * LD + 1024 + h * HDm + c0;
      const float* vsrc = qkv + base + (size_t)(kr0 + j) * LD + 2048 + h * HDm + c0;
#pragma unroll
      for (int v4 = 0; v4 < 4; ++v4) {
        float4 f = ((const float4*)ksrc)[v4];
        ks[c0 + v4 * 4 + 0][j] = f.x;
        ks[c0 + v4 * 4 + 1][j] = f.y;
        ks[c0 + v4 * 4 + 2][j] = f.z;
        ks[c0 + v4 * 4 + 3][j] = f.w;
        float4 fv = ((const float4*)vsrc)[v4];
        *(float4*)&vs[j][c0 + v4 * 4] = fv;
      }
    }
    __syncthreads();

    // s = q k^T (4x4 per thread)
    float s[4][4] = {};
#pragma unroll 16
    for (int d = 0; d < 64; ++d) {
      float ar[4], br[4];
#pragma unroll
      for (int i = 0; i < 4; ++i) ar[i] = qs[d][ty * 4 + i];
#pragma unroll
      for (int j = 0; j < 4; ++j) br[j] = ks[d][tx * 4 + j];
#pragma unroll
      for (int i = 0; i < 4; ++i)
#pragma unroll
        for (int j = 0; j < 4; ++j) s[i][j] += ar[i] * br[j];
    }

    // online softmax (row stats reduced over the 16 tx lanes, same wave)
#pragma unroll
    for (int i = 0; i < 4; ++i) {
      float mt = -INFINITY;
#pragma unroll
      for (int j = 0; j < 4; ++j) { s[i][j] *= scale; mt = fmaxf(mt, s[i][j]); }
      for (int off = 1; off < 16; off <<= 1) mt = fmaxf(mt, __shfl_xor(mt, off));
      float mnew = fmaxf(m_i[i], mt);
      float alpha = __expf(m_i[i] - mnew);
      float rs = 0.f;
#pragma unroll
      for (int j = 0; j < 4; ++j) { s[i][j] = __expf(s[i][j] - mnew); rs += s[i][j]; }
      for (int off = 1; off < 16; off <<= 1) rs += __shfl_xor(rs, off);
      l_i[i] = l_i[i] * alpha + rs;
      m_i[i] = mnew;
#pragma unroll
      for (int d = 0; d < 4; ++d) o[i][d] *= alpha;
      // store p to LDS (swizzled to break bank conflicts on the PV read)
      int irow = ty * 4 + i;
#pragma unroll
      for (int j = 0; j < 4; ++j)
        ps[irow][((irow << 2) + tx * 4 + j) & 63] = s[i][j];
    }
    __syncthreads();

    // o += p v
#pragma unroll 16
    for (int j = 0; j < 64; ++j) {
      float pr[4], vr[4];
#pragma unroll
      for (int i = 0; i < 4; ++i) {
        int irow = ty * 4 + i;
        pr[i] = ps[irow][((irow << 2) + j) & 63];
      }
#pragma unroll
      for (int d = 0; d < 4; ++d) vr[d] = vs[j][tx * 4 + d];
#pragma unroll
      for (int i = 0; i < 4; ++i)
#pragma unroll
        for (int d = 0; d < 4; ++d) o[i][d] += pr[i] * vr[d];
    }
  }

  // write out into the q band (cols h*64..h*64+63) — only this block read them
#pragma unroll
  for (int i = 0; i < 4; ++i) {
    float inv = 1.0f / l_i[i];
    float4 f;
    f.x = o[i][0] * inv; f.y = o[i][1] * inv; f.z = o[i][2] * inv; f.w = o[i][3] * inv;
    float* dst = qkv + base + (size_t)(q0 + ty * 4 + i) * LD + h * HDm + tx * 4;
    *(float4*)dst = f;
  }
}

// ---------------------------------------------------------------------------
extern "C" void kernel_launch(void* const* d_in, const int* in_sizes, int n_in,
                              void* d_out, int out_size, void* d_ws, size_t ws_size,
                              hipStream_t stream) {
  (void)in_sizes; (void)n_in; (void)out_size; (void)ws_size;
  const float* x       = (const float*)d_in[0];   // 8x1024x1024
  const float* W_qkv   = (const float*)d_in[1];   // 3072x1024
  const float* W_proj  = (const float*)d_in[2];   // 1024x1024
  const float* b_proj  = (const float*)d_in[3];   // 1024
  const float* coef_k  = (const float*)d_in[4];   // 10x3000
  const float* coef_v  = (const float*)d_in[5];   // 10x3000
  const int*   indices = (const int*)d_in[6];     // 10x3000
  const int*   task    = (const int*)d_in[7];     // scalar

  float* ws  = (float*)d_ws;
  float* Bm  = ws;                        // 1M floats
  float* U   = ws + (1u << 20);           // 1M
  float* Wk  = ws + (2u << 20);           // 1M
  float* Wv  = ws + (3u << 20);           // 1M
  float* qkv = ws + (4u << 20);           // 8192*3072 = 24M  (total 112 MB)

  // DCT basis
  dct_kernel<<<4096, 256, 0, stream>>>(Bm);

  // Wk = Bm^T (S_k @ Bm)
  hipMemsetAsync(U, 0, (size_t)1048576 * 4, stream);
  scatter_kernel<<<10 * NFRQ, 256, 0, stream>>>(coef_k, indices, task, Bm, U);
  gemm_tn<<<dim3(16, 16), 256, 0, stream>>>(Bm, U, Wk, 1024, 1024, 1024, 1024);

  // Wv = Bm^T (S_v @ Bm)
  hipMemsetAsync(U, 0, (size_t)1048576 * 4, stream);
  scatter_kernel<<<10 * NFRQ, 256, 0, stream>>>(coef_v, indices, task, Bm, U);
  gemm_tn<<<dim3(16, 16), 256, 0, stream>>>(Bm, U, Wv, 1024, 1024, 1024, 1024);

  // qkv = x @ W_qkv^T ; k band += x @ Wk^T ; v band += x @ Wv^T
  gemm_nt<<<dim3(48, 128), 256, 0, stream>>>(x, W_qkv, qkv, 1024, 1024, 1024, 3072, 0, nullptr);
  gemm_nt<<<dim3(16, 128), 256, 0, stream>>>(x, Wk, qkv + 1024, 1024, 1024, 1024, 3072, 1, nullptr);
  gemm_nt<<<dim3(16, 128), 256, 0, stream>>>(x, Wv, qkv + 2048, 1024, 1024, 1024, 3072, 1, nullptr);

  // attention (writes result into the q band in-place)
  attn_kernel<<<dim3(16, 128), 256, 0, stream>>>(qkv);

  // out = attn_out @ W_proj^T + b_proj   (attn_out = q band, lda=3072)
  gemm_nt<<<dim3(16, 128), 256, 0, stream>>>(qkv, W_proj, (float*)d_out,
                                             1024, 3072, 1024, 1024, 0, b_proj);
}

// Round 2
// 1737.357 us; speedup vs baseline: 1.6432x; 1.6432x over previous
//
#include <hip/hip_runtime.h>
#include <math.h>

// Problem constants (B=8, N=1024, C=1024, H=16, hd=64, n_tasks=10, n_frq=3000)
#define NFRQ 3000

// ---------------------------------------------------------------------------
// DCT-II orthonormal matrix, computed in double for accuracy headroom.
__global__ __launch_bounds__(256) void dct_kernel(float* __restrict__ Bm) {
  int t = blockIdx.x * 256 + threadIdx.x;       // 0 .. 1M-1
  int i = t >> 10, j = t & 1023;
  double v;
  if (i == 0)
    v = sqrt(1.0 / 1024.0);
  else
    v = sqrt(2.0 / 1024.0) *
        cos(3.14159265358979323846 * (double)i * (2.0 * (double)j + 1.0) / 2048.0);
  Bm[t] = (float)v;
}

// ---------------------------------------------------------------------------
// U = S @ Bm where S is the sparse scatter of coef at idx (tasks 0..*task).
// One block per nonzero: U[r,:] += val * Bm[c,:]
__global__ __launch_bounds__(256) void scatter_kernel(const float* __restrict__ coef,
                                                      const int* __restrict__ idx,
                                                      const int* __restrict__ task,
                                                      const float* __restrict__ Bm,
                                                      float* __restrict__ U) {
  int nz = blockIdx.x;                          // 0 .. 29999
  if (nz / NFRQ > *task) return;                // tasks 0..task participate
  float val = coef[nz];
  int id = idx[nz];
  int r = id >> 10, c = id & 1023;
  const float* brow = Bm + ((size_t)c << 10);
  float* urow = U + ((size_t)r << 10);
  for (int j = (int)threadIdx.x; j < 1024; j += 256)
    atomicAdd(urow + j, val * brow[j]);
}

// ---------------------------------------------------------------------------
// C[MxN] (+)= A^T B : A is KxM (lda=M), B is KxN (ldb=N). 64x64 tile, 4x4/thr.
__global__ __launch_bounds__(256) void gemm_tn(const float* __restrict__ A,
                                               const float* __restrict__ B,
                                               float* __restrict__ C,
                                               int K, int lda, int ldb, int ldc,
                                               int beta) {
  __shared__ float As[16][68];
  __shared__ float Bs[16][68];
  int t = threadIdx.x;
  int tx = t & 15, ty = t >> 4;
  int m0 = blockIdx.y * 64, n0 = blockIdx.x * 64;
  int kr = t >> 4;            // 0..15 : tile row
  int mc = (t & 15) << 2;     // 0..60 : tile col (x4)
  float acc[4][4] = {};
  for (int k0 = 0; k0 < K; k0 += 16) {
    float4 a4 = *(const float4*)(A + (size_t)(k0 + kr) * lda + m0 + mc);
    float4 b4 = *(const float4*)(B + (size_t)(k0 + kr) * ldb + n0 + mc);
    __syncthreads();
    *(float4*)&As[kr][mc] = a4;
    *(float4*)&Bs[kr][mc] = b4;
    __syncthreads();
#pragma unroll
    for (int k = 0; k < 16; ++k) {
      float ar[4], br[4];
#pragma unroll
      for (int i = 0; i < 4; ++i) ar[i] = As[k][ty * 4 + i];
#pragma unroll
      for (int j = 0; j < 4; ++j) br[j] = Bs[k][tx * 4 + j];
#pragma unroll
      for (int i = 0; i < 4; ++i)
#pragma unroll
        for (int j = 0; j < 4; ++j) acc[i][j] += ar[i] * br[j];
    }
  }
#pragma unroll
  for (int i = 0; i < 4; ++i) {
    float* crow = C + (size_t)(m0 + ty * 4 + i) * ldc + n0 + tx * 4;
#pragma unroll
    for (int j = 0; j < 4; ++j) {
      float v = acc[i][j];
      if (beta) v += crow[j];
      crow[j] = v;
    }
  }
}

// ---------------------------------------------------------------------------
// C[MxN] = A B^T (+bias) : A is MxK (lda), B is NxK (ldb). 128x128 tile,
// 8x8 per thread, ds_read_b128 fragments -> VALU-bound.
__global__ __launch_bounds__(256) void gemm_nt128(const float* __restrict__ A,
                                                  const float* __restrict__ B,
                                                  float* __restrict__ C,
                                                  int K, int lda, int ldb, int ldc,
                                                  const float* __restrict__ bias) {
  __shared__ float As[16][132];   // As[k][m], pad 4 words
  __shared__ float Bs[16][132];   // Bs[k][n]
  int t = threadIdx.x;
  int tx = t & 15, ty = t >> 4;
  int m0 = blockIdx.y * 128, n0 = blockIdx.x * 128;
  int r0 = t >> 2;                // 0..63 : tile row (first half)
  int kq = (t & 3) << 2;          // 0,4,8,12 : k offset (x4)
  const float* aptr = A + (size_t)(m0 + r0) * lda + kq;
  const float* bptr = B + (size_t)(n0 + r0) * ldb + kq;
  float acc[8][8] = {};
  for (int k0 = 0; k0 < K; k0 += 16) {
    float4 a0 = *(const float4*)(aptr + k0);
    float4 a1 = *(const float4*)(aptr + (size_t)64 * lda + k0);
    float4 b0 = *(const float4*)(bptr + k0);
    float4 b1 = *(const float4*)(bptr + (size_t)64 * ldb + k0);
    __syncthreads();
    As[kq + 0][r0] = a0.x; As[kq + 1][r0] = a0.y;
    As[kq + 2][r0] = a0.z; As[kq + 3][r0] = a0.w;
    As[kq + 0][r0 + 64] = a1.x; As[kq + 1][r0 + 64] = a1.y;
    As[kq + 2][r0 + 64] = a1.z; As[kq + 3][r0 + 64] = a1.w;
    Bs[kq + 0][r0] = b0.x; Bs[kq + 1][r0] = b0.y;
    Bs[kq + 2][r0] = b0.z; Bs[kq + 3][r0] = b0.w;
    Bs[kq + 0][r0 + 64] = b1.x; Bs[kq + 1][r0 + 64] = b1.y;
    Bs[kq + 2][r0 + 64] = b1.z; Bs[kq + 3][r0 + 64] = b1.w;
    __syncthreads();
#pragma unroll
    for (int k = 0; k < 16; ++k) {
      float ar[8], br[8];
      *(float4*)&ar[0] = *(const float4*)&As[k][ty * 8];
      *(float4*)&ar[4] = *(const float4*)&As[k][ty * 8 + 4];
      *(float4*)&br[0] = *(const float4*)&Bs[k][tx * 8];
      *(float4*)&br[4] = *(const float4*)&Bs[k][tx * 8 + 4];
#pragma unroll
      for (int i = 0; i < 8; ++i)
#pragma unroll
        for (int j = 0; j < 8; ++j) acc[i][j] += ar[i] * br[j];
    }
  }
#pragma unroll
  for (int i = 0; i < 8; ++i) {
    float* crow = C + (size_t)(m0 + ty * 8 + i) * ldc + n0 + tx * 8;
    float4 v0, v1;
    v0.x = acc[i][0]; v0.y = acc[i][1]; v0.z = acc[i][2]; v0.w = acc[i][3];
    v1.x = acc[i][4]; v1.y = acc[i][5]; v1.z = acc[i][6]; v1.w = acc[i][7];
    if (bias) {
      const float* bp = bias + n0 + tx * 8;
      v0.x += bp[0]; v0.y += bp[1]; v0.z += bp[2]; v0.w += bp[3];
      v1.x += bp[4]; v1.y += bp[5]; v1.z += bp[6]; v1.w += bp[7];
    }
    *(float4*)crow = v0;
    *(float4*)(crow + 4) = v1;
  }
}

// ---------------------------------------------------------------------------
// Flash-style attention. qkv: (8*1024) x 3072 [q | k | v bands of 1024 cols].
// One block = one (b,h) and a 64-row q tile. Writes softmax(qk^T*s)@v into the
// q band in-place (each block writes exactly the cells only it has read).
__global__ __launch_bounds__(256) void attn_kernel(float* qkv) {
  const int LD = 3072, Nn = 1024, HDm = 64;
  __shared__ float qs[64][64];   // transposed: qs[d][i]
  __shared__ float ks[64][64];   // transposed: ks[d][j]
  __shared__ float vs[64][64];   // row-major:  vs[j][d]
  __shared__ float ps[64][64];   // swizzled:   ps[i][(j+4i)&63]
  int t = threadIdx.x;
  int tx = t & 15, ty = t >> 4;
  int b = blockIdx.y >> 4, h = blockIdx.y & 15;
  int q0 = blockIdx.x * 64;
  const float scale = 0.125f;    // hd^-0.5
  size_t base = (size_t)b * Nn * LD;

  // load q tile (transposed into LDS)
  {
    int i = t >> 2, c0 = (t & 3) << 4;
    const float* src = qkv + base + (size_t)(q0 + i) * LD + h * HDm + c0;
#pragma unroll
    for (int v4 = 0; v4 < 4; ++v4) {
      float4 f = ((const float4*)src)[v4];
      qs[c0 + v4 * 4 + 0][i] = f.x;
      qs[c0 + v4 * 4 + 1][i] = f.y;
      qs[c0 + v4 * 4 + 2][i] = f.z;
      qs[c0 + v4 * 4 + 3][i] = f.w;
    }
  }

  float m_i[4], l_i[4], o[4][4];
#pragma unroll
  for (int i = 0; i < 4; ++i) {
    m_i[i] = -INFINITY; l_i[i] = 0.f;
#pragma unroll
    for (int d = 0; d < 4; ++d) o[i][d] = 0.f;
  }

  for (int kt = 0; kt < 16; ++kt) {
    int kr0 = kt * 64;
    __syncthreads();   // prev iter done with ks/vs/ps (also covers q-store @kt=0)
    {
      int j = t >> 2, c0 = (t & 3) << 4;
      const float* ksrc = qkv + base + (size_t)(kr0 + j) * LD + 1024 + h * HDm + c0;
      const float* vsrc = qkv + base + (size_t)(kr0 + j) * LD + 2048 + h * HDm + c0;
#pragma unroll
      for (int v4 = 0; v4 < 4; ++v4) {
        float4 f = ((const float4*)ksrc)[v4];
        ks[c0 + v4 * 4 + 0][j] = f.x;
        ks[c0 + v4 * 4 + 1][j] = f.y;
        ks[c0 + v4 * 4 + 2][j] = f.z;
        ks[c0 + v4 * 4 + 3][j] = f.w;
        float4 fv = ((const float4*)vsrc)[v4];
        *(float4*)&vs[j][c0 + v4 * 4] = fv;
      }
    }
    __syncthreads();

    // s = q k^T (4x4 per thread)
    float s[4][4] = {};
#pragma unroll 16
    for (int d = 0; d < 64; ++d) {
      float ar[4], br[4];
#pragma unroll
      for (int i = 0; i < 4; ++i) ar[i] = qs[d][ty * 4 + i];
#pragma unroll
      for (int j = 0; j < 4; ++j) br[j] = ks[d][tx * 4 + j];
#pragma unroll
      for (int i = 0; i < 4; ++i)
#pragma unroll
        for (int j = 0; j < 4; ++j) s[i][j] += ar[i] * br[j];
    }

    // online softmax (row stats reduced over the 16 tx lanes, same wave)
#pragma unroll
    for (int i = 0; i < 4; ++i) {
      float mt = -INFINITY;
#pragma unroll
      for (int j = 0; j < 4; ++j) { s[i][j] *= scale; mt = fmaxf(mt, s[i][j]); }
      for (int off = 1; off < 16; off <<= 1) mt = fmaxf(mt, __shfl_xor(mt, off));
      float mnew = fmaxf(m_i[i], mt);
      float alpha = __expf(m_i[i] - mnew);
      float rs = 0.f;
#pragma unroll
      for (int j = 0; j < 4; ++j) { s[i][j] = __expf(s[i][j] - mnew); rs += s[i][j]; }
      for (int off = 1; off < 16; off <<= 1) rs += __shfl_xor(rs, off);
      l_i[i] = l_i[i] * alpha + rs;
      m_i[i] = mnew;
#pragma unroll
      for (int d = 0; d < 4; ++d) o[i][d] *= alpha;
      // store p to LDS (swizzled to break bank conflicts on the PV read)
      int irow = ty * 4 + i;
#pragma unroll
      for (int j = 0; j < 4; ++j)
        ps[irow][((irow << 2) + tx * 4 + j) & 63] = s[i][j];
    }
    __syncthreads();

    // o += p v
#pragma unroll 16
    for (int j = 0; j < 64; ++j) {
      float pr[4], vr[4];
#pragma unroll
      for (int i = 0; i < 4; ++i) {
        int irow = ty * 4 + i;
        pr[i] = ps[irow][((irow << 2) + j) & 63];
      }
#pragma unroll
      for (int d = 0; d < 4; ++d) vr[d] = vs[j][tx * 4 + d];
#pragma unroll
      for (int i = 0; i < 4; ++i)
#pragma unroll
        for (int d = 0; d < 4; ++d) o[i][d] += pr[i] * vr[d];
    }
  }

  // write out into the q band (cols h*64..h*64+63) — only this block read them
#pragma unroll
  for (int i = 0; i < 4; ++i) {
    float inv = 1.0f / l_i[i];
    float4 f;
    f.x = o[i][0] * inv; f.y = o[i][1] * inv; f.z = o[i][2] * inv; f.w = o[i][3] * inv;
    float* dst = qkv + base + (size_t)(q0 + ty * 4 + i) * LD + h * HDm + tx * 4;
    *(float4*)dst = f;
  }
}

// ---------------------------------------------------------------------------
extern "C" void kernel_launch(void* const* d_in, const int* in_sizes, int n_in,
                              void* d_out, int out_size, void* d_ws, size_t ws_size,
                              hipStream_t stream) {
  (void)in_sizes; (void)n_in; (void)out_size; (void)ws_size;
  const float* x       = (const float*)d_in[0];   // 8x1024x1024
  const float* W_qkv   = (const float*)d_in[1];   // 3072x1024
  const float* W_proj  = (const float*)d_in[2];   // 1024x1024
  const float* b_proj  = (const float*)d_in[3];   // 1024
  const float* coef_k  = (const float*)d_in[4];   // 10x3000
  const float* coef_v  = (const float*)d_in[5];   // 10x3000
  const int*   indices = (const int*)d_in[6];     // 10x3000
  const int*   task    = (const int*)d_in[7];     // scalar

  // Workspace layout (floats). Bm/U live inside the future qkv region — they
  // are fully consumed before the big GEMM writes qkv. Peak = 27M fl = 108 MB.
  float* ws    = (float*)d_ws;
  float* qkv   = ws;                      // [0, 24M)  : 8192 x 3072
  float* Bm    = ws;                      // [0, 1M)   : transient
  float* U     = ws + (1u << 20);         // [1M, 2M)  : transient
  float* Wcomb = ws + (24u << 20);        // [24M, 27M): 3072 x 1024

  // DCT basis
  dct_kernel<<<4096, 256, 0, stream>>>(Bm);

  // Wcomb = W_qkv; then += LoRA weights into the k and v bands
  hipMemcpyAsync(Wcomb, W_qkv, (size_t)3072 * 1024 * 4, hipMemcpyDeviceToDevice, stream);

  // Wcomb_k += Bm^T (S_k @ Bm)
  hipMemsetAsync(U, 0, (size_t)1048576 * 4, stream);
  scatter_kernel<<<10 * NFRQ, 256, 0, stream>>>(coef_k, indices, task, Bm, U);
  gemm_tn<<<dim3(16, 16), 256, 0, stream>>>(Bm, U, Wcomb + (1u << 20),
                                            1024, 1024, 1024, 1024, 1);

  // Wcomb_v += Bm^T (S_v @ Bm)
  hipMemsetAsync(U, 0, (size_t)1048576 * 4, stream);
  scatter_kernel<<<10 * NFRQ, 256, 0, stream>>>(coef_v, indices, task, Bm, U);
  gemm_tn<<<dim3(16, 16), 256, 0, stream>>>(Bm, U, Wcomb + (2u << 20),
                                            1024, 1024, 1024, 1024, 1);

  // qkv = x @ Wcomb^T   (single fused 8192 x 3072 x 1024 GEMM)
  gemm_nt128<<<dim3(24, 64), 256, 0, stream>>>(x, Wcomb, qkv,
                                               1024, 1024, 1024, 3072, nullptr);

  // attention (writes result into the q band in-place)
  attn_kernel<<<dim3(16, 128), 256, 0, stream>>>(qkv);

  // out = attn_out @ W_proj^T + b_proj   (attn_out = q band, lda=3072)
  gemm_nt128<<<dim3(8, 64), 256, 0, stream>>>(qkv, W_proj, (float*)d_out,
                                              1024, 3072, 1024, 1024, b_proj);
}

// Round 3
// 513.954 us; speedup vs baseline: 5.5547x; 3.3804x over previous
//
#include <hip/hip_runtime.h>
#include <math.h>

// B=8, N=1024, C=1024, H=16, hd=64, n_tasks=10, n_frq=3000
#define NFRQ 3000

typedef __bf16 bf16;
typedef __attribute__((ext_vector_type(8))) __bf16 bf16x8;
typedef __attribute__((ext_vector_type(4))) __bf16 bf16x4;
typedef __attribute__((ext_vector_type(4))) float floatx4;

__device__ __forceinline__ floatx4 mfma16(bf16x8 a, bf16x8 b, floatx4 c) {
  return __builtin_amdgcn_mfma_f32_16x16x32_bf16(a, b, c, 0, 0, 0);
}

// async global->LDS, 16B per lane, dest = base + lane*16
__device__ __forceinline__ void async_load16(const bf16* g, bf16* l) {
  __builtin_amdgcn_global_load_lds(
      (const __attribute__((address_space(1))) unsigned int*)g,
      (__attribute__((address_space(3))) unsigned int*)l, 16, 0, 0);
}

// ---------------------------------------------------------------------------
// DCT-II orthonormal matrix. Exact integer angle reduction: i*(2j+1) mod 4096.
// Writes Bm fp32 (for fp32 scatter) and Bmtb = Bm^T in bf16 (GEMM B operand).
__global__ __launch_bounds__(256) void dct_kernel(float* __restrict__ Bm,
                                                  bf16* __restrict__ Bmtb) {
  int t = blockIdx.x * 256 + threadIdx.x;  // 0..1M-1
  int i = t >> 10, j = t & 1023;
  const float cst = 0.04419417382415922f;       // sqrt(2)/32
  const float w = 1.5339807878856412e-3f;       // pi/2048
  int K1 = (i * (2 * j + 1)) & 4095;
  float v1 = (i == 0) ? 0.03125f : cst * __cosf((float)K1 * w);
  Bm[t] = v1;
  int K2 = (j * (2 * i + 1)) & 4095;            // Bm[j][i]
  float v2 = (j == 0) ? 0.03125f : cst * __cosf((float)K2 * w);
  Bmtb[t] = (__bf16)v2;
}

// ---------------------------------------------------------------------------
// U = S^T @ Bm for both coef sets (shared indices). U has 2 fp32 planes (k,v).
// For nz (r,c,val): U[c][:] += val * Bm[r][:]
__global__ __launch_bounds__(256) void scatter2(const float* __restrict__ coef_k,
                                                const float* __restrict__ coef_v,
                                                const int* __restrict__ idx,
                                                const int* __restrict__ task,
                                                const float* __restrict__ Bm,
                                                float* __restrict__ U) {
  int nz = blockIdx.x;
  if (nz >= (*task + 1) * NFRQ) return;
  float vk = coef_k[nz], vv = coef_v[nz];
  int id = idx[nz];
  int r = id >> 10, c = id & 1023;
  const float* brow = Bm + ((size_t)r << 10);
  float* u0 = U + ((size_t)c << 10);
  float* u1 = u0 + (1u << 20);
  for (int jj = (int)threadIdx.x; jj < 1024; jj += 256) {
    float bv = brow[jj];
    atomicAdd(u0 + jj, vk * bv);
    atomicAdd(u1 + jj, vv * bv);
  }
}

// ---------------------------------------------------------------------------
// Ub[m][c] (bf16, m in [0,2048)) = U[plane=m>>10][c][m&1023]  (transpose+cvt)
__global__ __launch_bounds__(256) void transpose_u(const float* __restrict__ U,
                                                   bf16* __restrict__ Ub) {
  __shared__ float tile[64][65];
  int m0 = blockIdx.y * 64, c0 = blockIdx.x * 64;
  const float* src = U + ((size_t)(m0 >> 10) << 20);
  int mm0 = m0 & 1023;
  int t = threadIdx.x, r = t >> 2, cc = (t & 3) * 16;
#pragma unroll
  for (int i = 0; i < 4; ++i) {
    float4 f = *(const float4*)&src[(size_t)(c0 + r) * 1024 + mm0 + cc + i * 4];
    tile[r][cc + i * 4 + 0] = f.x; tile[r][cc + i * 4 + 1] = f.y;
    tile[r][cc + i * 4 + 2] = f.z; tile[r][cc + i * 4 + 3] = f.w;
  }
  __syncthreads();
  bf16x8 o0, o1;
#pragma unroll
  for (int i = 0; i < 8; ++i) o0[i] = (__bf16)tile[cc + i][r];
#pragma unroll
  for (int i = 0; i < 8; ++i) o1[i] = (__bf16)tile[cc + 8 + i][r];
  bf16* dst = Ub + (size_t)(m0 + r) * 1024 + c0 + cc;
  *(bf16x8*)&dst[0] = o0;
  *(bf16x8*)&dst[8] = o1;
}

// ---------------------------------------------------------------------------
// fp32 -> bf16 convert, n4 = n/4 float4 chunks
__global__ __launch_bounds__(256) void conv_bf16(const float* __restrict__ s,
                                                 bf16* __restrict__ d, int n4) {
  int i = blockIdx.x * 256 + threadIdx.x;
  if (i >= n4) return;
  float4 f = ((const float4*)s)[i];
  bf16x4 o = {(__bf16)f.x, (__bf16)f.y, (__bf16)f.z, (__bf16)f.w};
  *(bf16x4*)&d[(size_t)i * 4] = o;
}

// ---------------------------------------------------------------------------
// MFMA NT GEMM: C[m][n] = sum_k A[m][k]*B[n][k], K=1024 fixed, ldc=N.
// 128x128 block tile, 4 waves each 64x64 (4x4 of 16x16x32), m97 structure.
// Output: Cf!=null -> fp32 (+bias); else bf16 (+= addend fp32 if !=null).
__global__ __launch_bounds__(256) void gemm_bf16_nt(const bf16* __restrict__ A,
                                                    const bf16* __restrict__ B,
                                                    bf16* __restrict__ Cb,
                                                    float* __restrict__ Cf,
                                                    const float* __restrict__ addend,
                                                    const float* __restrict__ bias,
                                                    int N) {
  __shared__ bf16 As[4][128][8];   // [kchunk][m][8]
  __shared__ bf16 Bs[4][128][8];
  int t = threadIdx.x, w = t >> 6, lane = t & 63;
  int q15 = lane & 15, quad = lane >> 4;
  int m0 = blockIdx.y * 128, n0 = blockIdx.x * 128;
  int wm = (w >> 1) * 64, wn = (w & 1) * 64;
  floatx4 acc[4][4];
#pragma unroll
  for (int i = 0; i < 4; ++i)
#pragma unroll
    for (int j = 0; j < 4; ++j) acc[i][j] = (floatx4){0.f, 0.f, 0.f, 0.f};

  const bf16* Ag = A + (size_t)(m0 + lane) * 1024 + w * 8;
  const bf16* Bg = B + (size_t)(n0 + lane) * 1024 + w * 8;

  for (int k0 = 0; k0 < 1024; k0 += 32) {
    __syncthreads();
    async_load16(Ag + k0,             &As[w][0][0]);
    async_load16(Ag + 64 * 1024 + k0, &As[w][64][0]);
    async_load16(Bg + k0,             &Bs[w][0][0]);
    async_load16(Bg + 64 * 1024 + k0, &Bs[w][64][0]);
    __syncthreads();
    bf16x8 af[4], bfr[4];
#pragma unroll
    for (int i = 0; i < 4; ++i) af[i]  = *(const bf16x8*)&As[quad][wm + i * 16 + q15][0];
#pragma unroll
    for (int j = 0; j < 4; ++j) bfr[j] = *(const bf16x8*)&Bs[quad][wn + j * 16 + q15][0];
#pragma unroll
    for (int i = 0; i < 4; ++i)
#pragma unroll
      for (int j = 0; j < 4; ++j) acc[i][j] = mfma16(af[i], bfr[j], acc[i][j]);
  }

#pragma unroll
  for (int i = 0; i < 4; ++i)
#pragma unroll
    for (int r = 0; r < 4; ++r) {
      int gm = m0 + wm + i * 16 + quad * 4 + r;
      size_t rowo = (size_t)gm * N + n0 + wn;
#pragma unroll
      for (int j = 0; j < 4; ++j) {
        int col = j * 16 + q15;
        float v = acc[i][j][r];
        if (Cf) {
          Cf[rowo + col] = v + (bias ? bias[n0 + wn + col] : 0.f);
        } else {
          if (addend) v += addend[rowo + col];
          Cb[rowo + col] = (__bf16)v;
        }
      }
    }
}

// ---------------------------------------------------------------------------
// Vt[b][h][d][n] = qkvb[b*1024+n][2048 + h*64 + d]
__global__ __launch_bounds__(256) void vt_kernel(const bf16* __restrict__ qkvb,
                                                 bf16* __restrict__ Vt) {
  __shared__ bf16 tile[64][72];
  int bh = blockIdx.y, n0 = blockIdx.x * 64;
  int b = bh >> 4, h = bh & 15;
  int t = threadIdx.x, r = t >> 2, c = (t & 3) * 16;
  const bf16* src = qkvb + (size_t)(b * 1024 + n0 + r) * 3072 + 2048 + h * 64 + c;
  *(bf16x8*)&tile[r][c]     = *(const bf16x8*)&src[0];
  *(bf16x8*)&tile[r][c + 8] = *(const bf16x8*)&src[8];
  __syncthreads();
  bf16x8 o0, o1;
#pragma unroll
  for (int i = 0; i < 8; ++i) o0[i] = tile[c + i][r];
#pragma unroll
  for (int i = 0; i < 8; ++i) o1[i] = tile[c + 8 + i][r];
  bf16* dst = Vt + (size_t)(bh * 64 + r) * 1024 + n0 + c;
  *(bf16x8*)&dst[0] = o0;
  *(bf16x8*)&dst[8] = o1;
}

// ---------------------------------------------------------------------------
// Flash attention, S^T formulation. Block = (b,h,128 q rows), 4 waves, each
// wave owns 32 q columns of S^T. kv-tiles of 64 keys. Per kv-tile per wave:
// 16 MFMA (K Q^T) + softmax (in-lane + 2 shuffles) + 8 ds_write_b64 P^T
// + 16 MFMA (V^T P^T). Output O^T -> LDS transpose -> bf16 attn_out.
__global__ __launch_bounds__(256) void attn_mfma(const bf16* __restrict__ qkvb,
                                                 const bf16* __restrict__ Vt,
                                                 bf16* __restrict__ attn_out) {
  __shared__ __align__(16) char smem[49152];
  bf16 (*Qs)[128][8] = (bf16(*)[128][8])smem;            // 16KB [dchunk][q][8]
  bf16 (*Ks)[64][8]  = (bf16(*)[64][8])(smem + 16384);   // 8KB  [dchunk][key][8]
  bf16 (*Vs)[64][8]  = (bf16(*)[64][8])(smem + 24576);   // 8KB  [keychunk][d][8]
  bf16* PsB = (bf16*)(smem + 32768);                     // 16KB [w][nt][kc][q16][8]

  int t = threadIdx.x, w = t >> 6, lane = t & 63;
  int q15 = lane & 15, quad = lane >> 4;
  int bh = blockIdx.y, b = bh >> 4, h = bh & 15;
  int q0 = blockIdx.x * 128;
  const float scale = 0.125f;

  const bf16* Qg = qkvb + (size_t)(b * 1024 + q0) * 3072 + h * 64;
  const bf16* Kg = qkvb + (size_t)(b * 1024) * 3072 + 1024 + h * 64;
  const bf16* Vg = Vt + (size_t)(bh * 64) * 1024;

  // stage Q tile once: 16 chunks; wave w does kc = w*2, w*2+1 (both halves)
#pragma unroll
  for (int cc = 0; cc < 2; ++cc) {
    int kc = w * 2 + cc;
    async_load16(Qg + (size_t)lane * 3072 + kc * 8,        &Qs[kc][0][0]);
    async_load16(Qg + (size_t)(64 + lane) * 3072 + kc * 8, &Qs[kc][64][0]);
  }

  floatx4 oacc[4][2];
  float m_i[2], l_i[2];
#pragma unroll
  for (int nt = 0; nt < 2; ++nt) {
    m_i[nt] = -INFINITY; l_i[nt] = 0.f;
#pragma unroll
    for (int mt = 0; mt < 4; ++mt) oacc[mt][nt] = (floatx4){0.f, 0.f, 0.f, 0.f};
  }

  for (int kt = 0; kt < 16; ++kt) {
    int kv0 = kt * 64;
    __syncthreads();
    const bf16* Kg2 = Kg + (size_t)(kv0 + lane) * 3072;
    const bf16* Vg2 = Vg + (size_t)lane * 1024 + kv0;
    async_load16(Kg2 + (w * 2) * 8,     &Ks[w * 2][0][0]);
    async_load16(Kg2 + (w * 2 + 1) * 8, &Ks[w * 2 + 1][0][0]);
    async_load16(Vg2 + (w * 2) * 8,     &Vs[w * 2][0][0]);
    async_load16(Vg2 + (w * 2 + 1) * 8, &Vs[w * 2 + 1][0][0]);
    __syncthreads();

    // S^T[key][q] = sum_d K[key][d] Q[q][d]
    floatx4 sacc[4][2];
#pragma unroll
    for (int mt = 0; mt < 4; ++mt)
#pragma unroll
      for (int nt = 0; nt < 2; ++nt) sacc[mt][nt] = (floatx4){0.f, 0.f, 0.f, 0.f};
#pragma unroll
    for (int ks = 0; ks < 2; ++ks) {
      bf16x8 kf[4], qf[2];
#pragma unroll
      for (int mt = 0; mt < 4; ++mt)
        kf[mt] = *(const bf16x8*)&Ks[ks * 4 + quad][mt * 16 + q15][0];
#pragma unroll
      for (int nt = 0; nt < 2; ++nt)
        qf[nt] = *(const bf16x8*)&Qs[ks * 4 + quad][w * 32 + nt * 16 + q15][0];
#pragma unroll
      for (int mt = 0; mt < 4; ++mt)
#pragma unroll
        for (int nt = 0; nt < 2; ++nt) sacc[mt][nt] = mfma16(kf[mt], qf[nt], sacc[mt][nt]);
    }

    // online softmax per q (lane-owned column of S^T)
#pragma unroll
    for (int nt = 0; nt < 2; ++nt) {
      float mx = -INFINITY;
#pragma unroll
      for (int mt = 0; mt < 4; ++mt)
#pragma unroll
        for (int r = 0; r < 4; ++r) mx = fmaxf(mx, sacc[mt][nt][r]);
      mx = fmaxf(mx, __shfl_xor(mx, 16));
      mx = fmaxf(mx, __shfl_xor(mx, 32));
      float mnew = fmaxf(m_i[nt], mx * scale);
      float alpha = __expf(m_i[nt] - mnew);
      float rsum = 0.f;
#pragma unroll
      for (int mt = 0; mt < 4; ++mt)
#pragma unroll
        for (int r = 0; r < 4; ++r) {
          float p = __expf(sacc[mt][nt][r] * scale - mnew);
          sacc[mt][nt][r] = p;
          rsum += p;
        }
      rsum += __shfl_xor(rsum, 16);
      rsum += __shfl_xor(rsum, 32);
      l_i[nt] = l_i[nt] * alpha + rsum;
      m_i[nt] = mnew;
#pragma unroll
      for (int mt = 0; mt < 4; ++mt)
#pragma unroll
        for (int r = 0; r < 4; ++r) oacc[mt][nt][r] *= alpha;
    }

    // P^T -> per-wave LDS in B-frag layout: [w][nt][kc][q16][8keys]
#pragma unroll
    for (int nt = 0; nt < 2; ++nt)
#pragma unroll
      for (int mt = 0; mt < 4; ++mt) {
        bf16x4 pk = {(__bf16)sacc[mt][nt][0], (__bf16)sacc[mt][nt][1],
                     (__bf16)sacc[mt][nt][2], (__bf16)sacc[mt][nt][3]};
        int kc = mt * 2 + (quad >> 1);
        *(bf16x4*)&PsB[(size_t)(w * 2 + nt) * 1024 + kc * 128 + q15 * 8 + (quad & 1) * 4] = pk;
      }

    // O^T[d][q] += sum_key V^T[d][key] P^T[key][q]   (same-wave LDS RAW)
#pragma unroll
    for (int ks = 0; ks < 2; ++ks) {
      bf16x8 vf[4], pf[2];
#pragma unroll
      for (int mt = 0; mt < 4; ++mt)
        vf[mt] = *(const bf16x8*)&Vs[ks * 4 + quad][mt * 16 + q15][0];
#pragma unroll
      for (int nt = 0; nt < 2; ++nt)
        pf[nt] = *(const bf16x8*)&PsB[(size_t)(w * 2 + nt) * 1024 + (ks * 4 + quad) * 128 + q15 * 8];
#pragma unroll
      for (int mt = 0; mt < 4; ++mt)
#pragma unroll
        for (int nt = 0; nt < 2; ++nt) oacc[mt][nt] = mfma16(vf[mt], pf[nt], oacc[mt][nt]);
    }
  }

  // epilogue: normalize, transpose O^T via per-wave LDS, store bf16
  __syncthreads();   // all waves done with Qs/Ks reads (T overlaps them)
  bf16* T = (bf16*)smem + w * 2304;   // [32 q][72]
#pragma unroll
  for (int nt = 0; nt < 2; ++nt) {
    float inv = 1.f / l_i[nt];
#pragma unroll
    for (int mt = 0; mt < 4; ++mt) {
      bf16x4 pk = {(__bf16)(oacc[mt][nt][0] * inv), (__bf16)(oacc[mt][nt][1] * inv),
                   (__bf16)(oacc[mt][nt][2] * inv), (__bf16)(oacc[mt][nt][3] * inv)};
      *(bf16x4*)&T[(nt * 16 + q15) * 72 + mt * 16 + quad * 4] = pk;
    }
  }
  int row = lane >> 1, ch = (lane & 1) * 32;
  const bf16* Tr = T + row * 72 + ch;
  bf16* outp = attn_out + (size_t)(b * 1024 + q0 + w * 32 + row) * 1024 + h * 64 + ch;
#pragma unroll
  for (int i = 0; i < 4; ++i) *(bf16x8*)&outp[i * 8] = *(const bf16x8*)&Tr[i * 8];
}

// ---------------------------------------------------------------------------
extern "C" void kernel_launch(void* const* d_in, const int* in_sizes, int n_in,
                              void* d_out, int out_size, void* d_ws, size_t ws_size,
                              hipStream_t stream) {
  (void)in_sizes; (void)n_in; (void)out_size; (void)ws_size;
  const float* x       = (const float*)d_in[0];   // 8x1024x1024
  const float* W_qkv   = (const float*)d_in[1];   // 3072x1024
  const float* W_proj  = (const float*)d_in[2];   // 1024x1024
  const float* b_proj  = (const float*)d_in[3];   // 1024
  const float* coef_k  = (const float*)d_in[4];   // 10x3000
  const float* coef_v  = (const float*)d_in[5];   // 10x3000
  const int*   indices = (const int*)d_in[6];     // 10x3000
  const int*   task    = (const int*)d_in[7];     // scalar

  // Workspace (104 MB peak). attn_out aliases the dead Bm/U/Ub region.
  char* w8 = (char*)d_ws;
  float* Bm     = (float*)(w8);                  // 4MB
  float* U      = (float*)(w8 + (4u  << 20));    // 8MB (k,v planes)
  bf16*  Ub     = (bf16*) (w8 + (12u << 20));    // 4MB [2048][1024]
  bf16*  Bmtb   = (bf16*) (w8 + (16u << 20));    // 2MB
  bf16*  Wcb    = (bf16*) (w8 + (18u << 20));    // 6MB [3072][1024]
  bf16*  xb     = (bf16*) (w8 + (24u << 20));    // 16MB
  bf16*  qkvb   = (bf16*) (w8 + (40u << 20));    // 48MB [8192][3072]
  bf16*  Vt     = (bf16*) (w8 + (88u << 20));    // 16MB [128][64][1024]
  bf16*  attnout= (bf16*) (w8);                  // 16MB alias (Bm/U/Ub dead)

  dct_kernel<<<4096, 256, 0, stream>>>(Bm, Bmtb);

  hipMemsetAsync(U, 0, (size_t)8 << 20, stream);
  scatter2<<<10 * NFRQ, 256, 0, stream>>>(coef_k, coef_v, indices, task, Bm, U);
  transpose_u<<<dim3(16, 32), 256, 0, stream>>>(U, Ub);

  // bf16 conversions: q band of W_qkv, W_proj, x
  conv_bf16<<<1024, 256, 0, stream>>>(W_qkv, Wcb, 262144);
  bf16* Wpb = Vt;  // park W_proj bf16 in the not-yet-used Vt region? NO — Vt
  // is written before proj runs. Use tail of Ub region instead? Ub dead after
  // lora GEMM; but conv must happen before proj only. Place W_projb in the
  // Bmtb slot (dead after lora GEMM) — convert AFTER the lora GEMM.
  conv_bf16<<<8192, 256, 0, stream>>>(x, xb, 2097152);

  // k,v bands: Wcb[1024+m][n] = sum_c Ub[m][c]*Bmtb[n][c] + W_qkv[1024+m][n]
  gemm_bf16_nt<<<dim3(8, 16), 256, 0, stream>>>(Ub, Bmtb, Wcb + (1u << 20), nullptr,
                                                W_qkv + (1u << 20), nullptr, 1024);

  // W_proj -> bf16 (into Bmtb slot, now dead)
  bf16* Wprojb = Bmtb;
  conv_bf16<<<1024, 256, 0, stream>>>(W_proj, Wprojb, 262144);

  // qkv = xb @ Wcb^T  -> bf16 [8192][3072]
  gemm_bf16_nt<<<dim3(24, 64), 256, 0, stream>>>(xb, Wcb, qkvb, nullptr,
                                                 nullptr, nullptr, 3072);

  // V^T
  vt_kernel<<<dim3(16, 128), 256, 0, stream>>>(qkvb, Vt);

  // attention
  attn_mfma<<<dim3(8, 128), 256, 0, stream>>>(qkvb, Vt, attnout);

  // out = attn_out @ W_proj^T + b_proj  (fp32 out)
  gemm_bf16_nt<<<dim3(8, 64), 256, 0, stream>>>(attnout, Wprojb, nullptr, (float*)d_out,
                                                nullptr, b_proj, 1024);
}

// Round 4
// 501.962 us; speedup vs baseline: 5.6874x; 1.0239x over previous
//
#include <hip/hip_runtime.h>
#include <math.h>

// B=8, N=1024, C=1024, H=16, hd=64, n_tasks=10, n_frq=3000
#define NFRQ 3000

typedef __bf16 bf16;
typedef __attribute__((ext_vector_type(8))) __bf16 bf16x8;
typedef __attribute__((ext_vector_type(4))) __bf16 bf16x4;
typedef __attribute__((ext_vector_type(4))) float floatx4;

__device__ __forceinline__ floatx4 mfma16(bf16x8 a, bf16x8 b, floatx4 c) {
  return __builtin_amdgcn_mfma_f32_16x16x32_bf16(a, b, c, 0, 0, 0);
}

// async global->LDS, 16B per lane, dest = base + lane*16
__device__ __forceinline__ void async_load16(const bf16* g, bf16* l) {
  __builtin_amdgcn_global_load_lds(
      (const __attribute__((address_space(1))) unsigned int*)g,
      (__attribute__((address_space(3))) unsigned int*)l, 16, 0, 0);
}

// ---------------------------------------------------------------------------
// DCT-II orthonormal matrix. Exact integer angle reduction: i*(2j+1) mod 4096.
__global__ __launch_bounds__(256) void dct_kernel(float* __restrict__ Bm,
                                                  bf16* __restrict__ Bmtb) {
  int t = blockIdx.x * 256 + threadIdx.x;  // 0..1M-1
  int i = t >> 10, j = t & 1023;
  const float cst = 0.04419417382415922f;       // sqrt(2)/32
  const float w = 1.5339807878856412e-3f;       // pi/2048
  int K1 = (i * (2 * j + 1)) & 4095;
  float v1 = (i == 0) ? 0.03125f : cst * __cosf((float)K1 * w);
  Bm[t] = v1;
  int K2 = (j * (2 * i + 1)) & 4095;            // Bm[j][i]
  float v2 = (j == 0) ? 0.03125f : cst * __cosf((float)K2 * w);
  Bmtb[t] = (__bf16)v2;
}

// ---------------------------------------------------------------------------
// U = S^T @ Bm for both coef sets (shared indices). U has 2 fp32 planes (k,v).
__global__ __launch_bounds__(256) void scatter2(const float* __restrict__ coef_k,
                                                const float* __restrict__ coef_v,
                                                const int* __restrict__ idx,
                                                const int* __restrict__ task,
                                                const float* __restrict__ Bm,
                                                float* __restrict__ U) {
  int nz = blockIdx.x;
  if (nz >= (*task + 1) * NFRQ) return;
  float vk = coef_k[nz], vv = coef_v[nz];
  int id = idx[nz];
  int r = id >> 10, c = id & 1023;
  const float* brow = Bm + ((size_t)r << 10);
  float* u0 = U + ((size_t)c << 10);
  float* u1 = u0 + (1u << 20);
  for (int jj = (int)threadIdx.x; jj < 1024; jj += 256) {
    float bv = brow[jj];
    atomicAdd(u0 + jj, vk * bv);
    atomicAdd(u1 + jj, vv * bv);
  }
}

// ---------------------------------------------------------------------------
// Ub[m][c] (bf16, m in [0,2048)) = U[plane=m>>10][c][m&1023]  (transpose+cvt)
__global__ __launch_bounds__(256) void transpose_u(const float* __restrict__ U,
                                                   bf16* __restrict__ Ub) {
  __shared__ float tile[64][65];
  int m0 = blockIdx.y * 64, c0 = blockIdx.x * 64;
  const float* src = U + ((size_t)(m0 >> 10) << 20);
  int mm0 = m0 & 1023;
  int t = threadIdx.x, r = t >> 2, cc = (t & 3) * 16;
#pragma unroll
  for (int i = 0; i < 4; ++i) {
    float4 f = *(const float4*)&src[(size_t)(c0 + r) * 1024 + mm0 + cc + i * 4];
    tile[r][cc + i * 4 + 0] = f.x; tile[r][cc + i * 4 + 1] = f.y;
    tile[r][cc + i * 4 + 2] = f.z; tile[r][cc + i * 4 + 3] = f.w;
  }
  __syncthreads();
  bf16x8 o0, o1;
#pragma unroll
  for (int i = 0; i < 8; ++i) o0[i] = (__bf16)tile[cc + i][r];
#pragma unroll
  for (int i = 0; i < 8; ++i) o1[i] = (__bf16)tile[cc + 8 + i][r];
  bf16* dst = Ub + (size_t)(m0 + r) * 1024 + c0 + cc;
  *(bf16x8*)&dst[0] = o0;
  *(bf16x8*)&dst[8] = o1;
}

// ---------------------------------------------------------------------------
// fp32 -> bf16 convert, n4 = n/4 float4 chunks
__global__ __launch_bounds__(256) void conv_bf16(const float* __restrict__ s,
                                                 bf16* __restrict__ d, int n4) {
  int i = blockIdx.x * 256 + threadIdx.x;
  if (i >= n4) return;
  float4 f = ((const float4*)s)[i];
  bf16x4 o = {(__bf16)f.x, (__bf16)f.y, (__bf16)f.z, (__bf16)f.w};
  *(bf16x4*)&d[(size_t)i * 4] = o;
}

// ---------------------------------------------------------------------------
// MFMA NT GEMM: C[m][n] = sum_k A[m][k]*B[n][k], K=1024 fixed, ldc=N.
// 128x128 block tile, 4 waves each 64x64 (4x4 of 16x16x32). BK=64 K-steps:
// per wave per step 8 async_load16 + 16 ds_read_b128 + 32 MFMA, 16 barrier
// pairs total (vs 32 at BK=32) -> halved barrier-drain overhead.
// Output: Cf!=null -> fp32 (+bias); else bf16 (+= addend fp32 if !=null).
// If vt!=null: tiles with col>=2048 (v band) are stored TRANSPOSED into
// vt[((b<<10)|vchan)<<10 | n] instead of Cb (fuses the V^T transpose).
__global__ __launch_bounds__(256) void gemm_bf16_nt(const bf16* __restrict__ A,
                                                    const bf16* __restrict__ B,
                                                    bf16* __restrict__ Cb,
                                                    float* __restrict__ Cf,
                                                    const float* __restrict__ addend,
                                                    const float* __restrict__ bias,
                                                    bf16* __restrict__ vt,
                                                    int N) {
  __shared__ bf16 As[8][128][8];   // [kchunk][m][8]  16KB
  __shared__ bf16 Bs[8][128][8];   // 16KB
  int t = threadIdx.x, w = t >> 6, lane = t & 63;
  int q15 = lane & 15, quad = lane >> 4;
  int m0 = blockIdx.y * 128, n0 = blockIdx.x * 128;
  int wm = (w >> 1) * 64, wn = (w & 1) * 64;
  floatx4 acc[4][4];
#pragma unroll
  for (int i = 0; i < 4; ++i)
#pragma unroll
    for (int j = 0; j < 4; ++j) acc[i][j] = (floatx4){0.f, 0.f, 0.f, 0.f};

  const bf16* Ag0 = A + (size_t)(m0 + lane) * 1024;
  const bf16* Ag1 = Ag0 + (size_t)64 * 1024;
  const bf16* Bg0 = B + (size_t)(n0 + lane) * 1024;
  const bf16* Bg1 = Bg0 + (size_t)64 * 1024;

  for (int k0 = 0; k0 < 1024; k0 += 64) {
    __syncthreads();
    // wave w stages kchunks w and w+4 for both halves of A and B
    async_load16(Ag0 + k0 + w * 8,       &As[w][0][0]);
    async_load16(Ag1 + k0 + w * 8,       &As[w][64][0]);
    async_load16(Ag0 + k0 + (w + 4) * 8, &As[w + 4][0][0]);
    async_load16(Ag1 + k0 + (w + 4) * 8, &As[w + 4][64][0]);
    async_load16(Bg0 + k0 + w * 8,       &Bs[w][0][0]);
    async_load16(Bg1 + k0 + w * 8,       &Bs[w][64][0]);
    async_load16(Bg0 + k0 + (w + 4) * 8, &Bs[w + 4][0][0]);
    async_load16(Bg1 + k0 + (w + 4) * 8, &Bs[w + 4][64][0]);
    __syncthreads();
#pragma unroll
    for (int ks = 0; ks < 2; ++ks) {
      bf16x8 af[4], bfr[4];
#pragma unroll
      for (int i = 0; i < 4; ++i)
        af[i] = *(const bf16x8*)&As[ks * 4 + quad][wm + i * 16 + q15][0];
#pragma unroll
      for (int j = 0; j < 4; ++j)
        bfr[j] = *(const bf16x8*)&Bs[ks * 4 + quad][wn + j * 16 + q15][0];
#pragma unroll
      for (int i = 0; i < 4; ++i)
#pragma unroll
        for (int j = 0; j < 4; ++j) acc[i][j] = mfma16(af[i], bfr[j], acc[i][j]);
    }
  }

  if (vt && (n0 + wn) >= 2048) {
    // v band: store transposed into Vt. acc[i][j][0..3] = 4 consecutive
    // x-rows (n dim) at fixed channel -> contiguous bf16x4 in Vt.
#pragma unroll
    for (int i = 0; i < 4; ++i) {
      int gm = m0 + wm + i * 16 + quad * 4;          // x row (4 consecutive)
      int b = gm >> 10, n = gm & 1023;
#pragma unroll
      for (int j = 0; j < 4; ++j) {
        int vchan = (n0 + wn - 2048) + j * 16 + q15; // h*64+d
        bf16x4 pk = {(__bf16)acc[i][j][0], (__bf16)acc[i][j][1],
                     (__bf16)acc[i][j][2], (__bf16)acc[i][j][3]};
        *(bf16x4*)&vt[((((size_t)b << 10) | vchan) << 10) | n] = pk;
      }
    }
    return;
  }

#pragma unroll
  for (int i = 0; i < 4; ++i)
#pragma unroll
    for (int r = 0; r < 4; ++r) {
      int gm = m0 + wm + i * 16 + quad * 4 + r;
      size_t rowo = (size_t)gm * N + n0 + wn;
#pragma unroll
      for (int j = 0; j < 4; ++j) {
        int col = j * 16 + q15;
        float v = acc[i][j][r];
        if (Cf) {
          Cf[rowo + col] = v + (bias ? bias[n0 + wn + col] : 0.f);
        } else {
          if (addend) v += addend[rowo + col];
          Cb[rowo + col] = (__bf16)v;
        }
      }
    }
}

// ---------------------------------------------------------------------------
// Flash attention, S^T formulation. Block = (b,h,128 q rows), 4 waves, each
// wave owns 32 q columns of S^T. kv-tiles of 64 keys.
__global__ __launch_bounds__(256) void attn_mfma(const bf16* __restrict__ qkvb,
                                                 const bf16* __restrict__ Vt,
                                                 bf16* __restrict__ attn_out) {
  __shared__ __align__(16) char smem[49152];
  bf16 (*Qs)[128][8] = (bf16(*)[128][8])smem;            // 16KB [dchunk][q][8]
  bf16 (*Ks)[64][8]  = (bf16(*)[64][8])(smem + 16384);   // 8KB  [dchunk][key][8]
  bf16 (*Vs)[64][8]  = (bf16(*)[64][8])(smem + 24576);   // 8KB  [keychunk][d][8]
  bf16* PsB = (bf16*)(smem + 32768);                     // 16KB [w][nt][kc][q16][8]

  int t = threadIdx.x, w = t >> 6, lane = t & 63;
  int q15 = lane & 15, quad = lane >> 4;
  int bh = blockIdx.y, b = bh >> 4, h = bh & 15;
  int q0 = blockIdx.x * 128;
  const float scale = 0.125f;

  const bf16* Qg = qkvb + (size_t)(b * 1024 + q0) * 3072 + h * 64;
  const bf16* Kg = qkvb + (size_t)(b * 1024) * 3072 + 1024 + h * 64;
  const bf16* Vg = Vt + (size_t)(bh * 64) * 1024;

#pragma unroll
  for (int cc = 0; cc < 2; ++cc) {
    int kc = w * 2 + cc;
    async_load16(Qg + (size_t)lane * 3072 + kc * 8,        &Qs[kc][0][0]);
    async_load16(Qg + (size_t)(64 + lane) * 3072 + kc * 8, &Qs[kc][64][0]);
  }

  floatx4 oacc[4][2];
  float m_i[2], l_i[2];
#pragma unroll
  for (int nt = 0; nt < 2; ++nt) {
    m_i[nt] = -INFINITY; l_i[nt] = 0.f;
#pragma unroll
    for (int mt = 0; mt < 4; ++mt) oacc[mt][nt] = (floatx4){0.f, 0.f, 0.f, 0.f};
  }

  for (int kt = 0; kt < 16; ++kt) {
    int kv0 = kt * 64;
    __syncthreads();
    const bf16* Kg2 = Kg + (size_t)(kv0 + lane) * 3072;
    const bf16* Vg2 = Vg + (size_t)lane * 1024 + kv0;
    async_load16(Kg2 + (w * 2) * 8,     &Ks[w * 2][0][0]);
    async_load16(Kg2 + (w * 2 + 1) * 8, &Ks[w * 2 + 1][0][0]);
    async_load16(Vg2 + (w * 2) * 8,     &Vs[w * 2][0][0]);
    async_load16(Vg2 + (w * 2 + 1) * 8, &Vs[w * 2 + 1][0][0]);
    __syncthreads();

    floatx4 sacc[4][2];
#pragma unroll
    for (int mt = 0; mt < 4; ++mt)
#pragma unroll
      for (int nt = 0; nt < 2; ++nt) sacc[mt][nt] = (floatx4){0.f, 0.f, 0.f, 0.f};
#pragma unroll
    for (int ks = 0; ks < 2; ++ks) {
      bf16x8 kf[4], qf[2];
#pragma unroll
      for (int mt = 0; mt < 4; ++mt)
        kf[mt] = *(const bf16x8*)&Ks[ks * 4 + quad][mt * 16 + q15][0];
#pragma unroll
      for (int nt = 0; nt < 2; ++nt)
        qf[nt] = *(const bf16x8*)&Qs[ks * 4 + quad][w * 32 + nt * 16 + q15][0];
#pragma unroll
      for (int mt = 0; mt < 4; ++mt)
#pragma unroll
        for (int nt = 0; nt < 2; ++nt) sacc[mt][nt] = mfma16(kf[mt], qf[nt], sacc[mt][nt]);
    }

#pragma unroll
    for (int nt = 0; nt < 2; ++nt) {
      float mx = -INFINITY;
#pragma unroll
      for (int mt = 0; mt < 4; ++mt)
#pragma unroll
        for (int r = 0; r < 4; ++r) mx = fmaxf(mx, sacc[mt][nt][r]);
      mx = fmaxf(mx, __shfl_xor(mx, 16));
      mx = fmaxf(mx, __shfl_xor(mx, 32));
      float mnew = fmaxf(m_i[nt], mx * scale);
      float alpha = __expf(m_i[nt] - mnew);
      float rsum = 0.f;
#pragma unroll
      for (int mt = 0; mt < 4; ++mt)
#pragma unroll
        for (int r = 0; r < 4; ++r) {
          float p = __expf(sacc[mt][nt][r] * scale - mnew);
          sacc[mt][nt][r] = p;
          rsum += p;
        }
      rsum += __shfl_xor(rsum, 16);
      rsum += __shfl_xor(rsum, 32);
      l_i[nt] = l_i[nt] * alpha + rsum;
      m_i[nt] = mnew;
#pragma unroll
      for (int mt = 0; mt < 4; ++mt)
#pragma unroll
        for (int r = 0; r < 4; ++r) oacc[mt][nt][r] *= alpha;
    }

#pragma unroll
    for (int nt = 0; nt < 2; ++nt)
#pragma unroll
      for (int mt = 0; mt < 4; ++mt) {
        bf16x4 pk = {(__bf16)sacc[mt][nt][0], (__bf16)sacc[mt][nt][1],
                     (__bf16)sacc[mt][nt][2], (__bf16)sacc[mt][nt][3]};
        int kc = mt * 2 + (quad >> 1);
        *(bf16x4*)&PsB[(size_t)(w * 2 + nt) * 1024 + kc * 128 + q15 * 8 + (quad & 1) * 4] = pk;
      }

#pragma unroll
    for (int ks = 0; ks < 2; ++ks) {
      bf16x8 vf[4], pf[2];
#pragma unroll
      for (int mt = 0; mt < 4; ++mt)
        vf[mt] = *(const bf16x8*)&Vs[ks * 4 + quad][mt * 16 + q15][0];
#pragma unroll
      for (int nt = 0; nt < 2; ++nt)
        pf[nt] = *(const bf16x8*)&PsB[(size_t)(w * 2 + nt) * 1024 + (ks * 4 + quad) * 128 + q15 * 8];
#pragma unroll
      for (int mt = 0; mt < 4; ++mt)
#pragma unroll
        for (int nt = 0; nt < 2; ++nt) oacc[mt][nt] = mfma16(vf[mt], pf[nt], oacc[mt][nt]);
    }
  }

  __syncthreads();
  bf16* T = (bf16*)smem + w * 2304;   // [32 q][72]
#pragma unroll
  for (int nt = 0; nt < 2; ++nt) {
    float inv = 1.f / l_i[nt];
#pragma unroll
    for (int mt = 0; mt < 4; ++mt) {
      bf16x4 pk = {(__bf16)(oacc[mt][nt][0] * inv), (__bf16)(oacc[mt][nt][1] * inv),
                   (__bf16)(oacc[mt][nt][2] * inv), (__bf16)(oacc[mt][nt][3] * inv)};
      *(bf16x4*)&T[(nt * 16 + q15) * 72 + mt * 16 + quad * 4] = pk;
    }
  }
  int row = lane >> 1, ch = (lane & 1) * 32;
  const bf16* Tr = T + row * 72 + ch;
  bf16* outp = attn_out + (size_t)(b * 1024 + q0 + w * 32 + row) * 1024 + h * 64 + ch;
#pragma unroll
  for (int i = 0; i < 4; ++i) *(bf16x8*)&outp[i * 8] = *(const bf16x8*)&Tr[i * 8];
}

// ---------------------------------------------------------------------------
extern "C" void kernel_launch(void* const* d_in, const int* in_sizes, int n_in,
                              void* d_out, int out_size, void* d_ws, size_t ws_size,
                              hipStream_t stream) {
  (void)in_sizes; (void)n_in; (void)out_size; (void)ws_size;
  const float* x       = (const float*)d_in[0];   // 8x1024x1024
  const float* W_qkv   = (const float*)d_in[1];   // 3072x1024
  const float* W_proj  = (const float*)d_in[2];   // 1024x1024
  const float* b_proj  = (const float*)d_in[3];   // 1024
  const float* coef_k  = (const float*)d_in[4];   // 10x3000
  const float* coef_v  = (const float*)d_in[5];   // 10x3000
  const int*   indices = (const int*)d_in[6];     // 10x3000
  const int*   task    = (const int*)d_in[7];     // scalar

  // Workspace (104 MB peak). attn_out aliases the dead Bm/U/Ub region.
  char* w8 = (char*)d_ws;
  float* Bm     = (float*)(w8);                  // 4MB
  float* U      = (float*)(w8 + (4u  << 20));    // 8MB (k,v planes)
  bf16*  Ub     = (bf16*) (w8 + (12u << 20));    // 4MB [2048][1024]
  bf16*  Bmtb   = (bf16*) (w8 + (16u << 20));    // 2MB
  bf16*  Wcb    = (bf16*) (w8 + (18u << 20));    // 6MB [3072][1024]
  bf16*  xb     = (bf16*) (w8 + (24u << 20));    // 16MB
  bf16*  qkvb   = (bf16*) (w8 + (40u << 20));    // 48MB [8192][3072]
  bf16*  Vt     = (bf16*) (w8 + (88u << 20));    // 16MB [128][64][1024]
  bf16*  attnout= (bf16*) (w8);                  // 16MB alias (Bm/U/Ub dead)

  dct_kernel<<<4096, 256, 0, stream>>>(Bm, Bmtb);

  hipMemsetAsync(U, 0, (size_t)8 << 20, stream);
  scatter2<<<10 * NFRQ, 256, 0, stream>>>(coef_k, coef_v, indices, task, Bm, U);
  transpose_u<<<dim3(16, 32), 256, 0, stream>>>(U, Ub);

  conv_bf16<<<1024, 256, 0, stream>>>(W_qkv, Wcb, 262144);
  conv_bf16<<<8192, 256, 0, stream>>>(x, xb, 2097152);

  // k,v bands: Wcb[1024+m][n] = sum_c Ub[m][c]*Bmtb[n][c] + W_qkv[1024+m][n]
  gemm_bf16_nt<<<dim3(8, 16), 256, 0, stream>>>(Ub, Bmtb, Wcb + (1u << 20), nullptr,
                                                W_qkv + (1u << 20), nullptr, nullptr, 1024);

  // W_proj -> bf16 (into Bmtb slot, dead after lora GEMM)
  bf16* Wprojb = Bmtb;
  conv_bf16<<<1024, 256, 0, stream>>>(W_proj, Wprojb, 262144);

  // qkv = xb @ Wcb^T -> q,k bands bf16 into qkvb; v band transposed into Vt
  gemm_bf16_nt<<<dim3(24, 64), 256, 0, stream>>>(xb, Wcb, qkvb, nullptr,
                                                 nullptr, nullptr, Vt, 3072);

  // attention
  attn_mfma<<<dim3(8, 128), 256, 0, stream>>>(qkvb, Vt, attnout);

  // out = attn_out @ W_proj^T + b_proj  (fp32 out)
  gemm_bf16_nt<<<dim3(8, 64), 256, 0, stream>>>(attnout, Wprojb, nullptr, (float*)d_out,
                                                nullptr, b_proj, nullptr, 1024);
}